// Round 9
// baseline (164.062 us; speedup 1.0000x reference)
//
#include <hip/hip_runtime.h>

#define NB 8      // NUM_BLOCK
#define NT 500    // NUM_FRAME
#define NF 257    // NUM_BIN
#define NC 8      // NUM_CH
#define NNUL 4    // NUM_NULL
#define LOWF 5
#define HIGHF 70
#define S_CHUNK 10
#define WARM 6
#define N_CHUNK 50   // 500 / S_CHUNK
#define AL 0.35f

__device__ __forceinline__ float dot8(const float4& a0, const float4& a1,
                                      const float4& b0, const float4& b1) {
    return a0.x*b0.x + a0.y*b0.y + a0.z*b0.z + a0.w*b0.w
         + a1.x*b1.x + a1.y*b1.y + a1.z*b1.z + a1.w*b1.w;
}

// Kernel 1: EMA over a 10-frame chunk (+6 warm-up; alpha^7 ~ 6e-4 rel — work
// per output 1.6x vs R8's 2.0x). Quad butterfly dedup (R5/R8-verified).
// Depth-2 x prefetch: 3 rotating register buffers, load for t+3 issued each
// body -> ~2 bodies of L2-latency cover (R8's depth-1 covered only ~1 body).
// launch_bounds(512,2): VGPR cap 128 (empirical gfx950 rule: cap ~= 256/w;
// w>=4 caps <=64 and spills this body — R5/R6 disasters).
// Grid: (fh, b, chunk) = 800 blocks x 512 threads.
__global__ __launch_bounds__(512, 2) void dcf_ema_kernel(
    const float* __restrict__ x,           // (NB,NT,2,NF,NC) fp32
    const int* __restrict__ beam_id,       // (NB,)
    const float* __restrict__ targ_w,      // (8,2,NF,NC) fp32
    const float* __restrict__ null_w,      // (8,NNUL,2,NF,NC) fp32
    float* __restrict__ out,               // fp32: dcf (NB,NT,NF,NNUL) then targ (NB,NT,2,NF)
    float* __restrict__ ws)                // (NB*NT,5): phi_sum[n], psd_sum — pre-zeroed
{
    const int tid = threadIdx.x;
    const int bid = blockIdx.x;
    const int fh = bid & 1;                // 0 -> f in [0,128), 1 -> [128,257)
    const int b  = (bid >> 1) & 7;
    const int k  = bid >> 4;
    const int t0 = k * S_CHUNK;
    const int te = t0 + S_CHUNK;           // 500 = 50*10, always exact
    int ts = t0 - WARM; if (ts < 0) ts = 0;

    const int f = fh * 128 + (tid >> 2);   // 0..255
    const int n = tid & 3;
    const int wid = tid >> 6;
    const int lane = tid & 63;
    const bool extra = (fh == 1) && (tid < 4);   // quad 0 of wave 0 -> f=256

    __shared__ float s_w256[16 + 4 * 16];  // f=256 weights: twr,twi then per-n nwr,nwi

    const int beam = beam_id[b];
    const int pA = n & 1;                  // lane's "A" part: 0=real(even n), 1=imag(odd n)
    const int offA = pA * (NF * NC);
    const int offB = (1 - pA) * (NF * NC);
    const int psel = (n == 1 || n == 2) ? 1 : 0;   // targ part for this lane's partial
    const float nsign = pA ? -1.f : 1.f;

    // weights in registers: 6 float4 per thread
    float4 tw0, tw1, nwA0, nwA1, nwB0, nwB1;
    {
        const float* tp = targ_w + ((size_t)(beam * 2 + psel) * NF + f) * NC;
        tw0 = *(const float4*)(tp);  tw1 = *(const float4*)(tp + 4);
        const float* qp = null_w + ((size_t)((beam * NNUL + n) * 2) * NF + f) * NC;
        nwA0 = *(const float4*)(qp + offA);  nwA1 = *(const float4*)(qp + offA + 4);
        nwB0 = *(const float4*)(qp + offB);  nwB1 = *(const float4*)(qp + offB + 4);
    }
    if (tid < 16) {
        int p = tid >> 3, c = tid & 7;
        s_w256[tid] = targ_w[((size_t)(beam * 2 + p) * NF + 256) * NC + c];
    } else if (tid < 80) {
        int i = tid - 16;
        int nn = i >> 4, p = (i >> 3) & 1, c = i & 7;
        s_w256[tid] = null_w[((size_t)((beam * NNUL + nn) * 2 + p) * NF + 256) * NC + c];
    }
    __syncthreads();   // only block-wide barrier

    float phi_r = 0.f, phi_i = 0.f, psd = 0.f;
    float phi_r2 = 0.f, phi_i2 = 0.f, psd2 = 0.f;
    const float a = AL, oma = 1.0f - AL;
    const size_t rowlen = 2 * NF * NC;     // 4112 floats per (b,t)
    const bool in_red = (f >= LOWF) && (f < HIGHF);   // only in fh==0 waves 0..4

    // depth-2 prefetch: buffers for frames t (a*), t+1 (b*), t+2 (c*).
    // te-ts >= 10 so the three unconditional preloads are in-range.
    const float* xp = x + (size_t)(b * NT + ts) * rowlen + f * NC;
    float4 aA0 = *(const float4*)(xp + offA);
    float4 aA1 = *(const float4*)(xp + offA + 4);
    float4 aB0 = *(const float4*)(xp + offB);
    float4 aB1 = *(const float4*)(xp + offB + 4);
    xp += rowlen;
    float4 bA0 = *(const float4*)(xp + offA);
    float4 bA1 = *(const float4*)(xp + offA + 4);
    float4 bB0 = *(const float4*)(xp + offB);
    float4 bB1 = *(const float4*)(xp + offB + 4);
    xp += rowlen;
    float4 cA0 = *(const float4*)(xp + offA);
    float4 cA1 = *(const float4*)(xp + offA + 4);
    float4 cB0 = *(const float4*)(xp + offB);
    float4 cB1 = *(const float4*)(xp + offB + 4);
    xp += rowlen;   // now points at frame ts+3

    float* outT = out + (size_t)NB * NT * NF * NNUL;

    #pragma unroll 3
    for (int t = ts; t < te; ++t) {
        // targ dots via quad butterfly: lane n's partial d covers
        // n0: xr.twr  n1: xi.twi  n2: xr.twi  n3: xi.twr
        const float d = dot8(aA0, aA1, tw0, tw1);
        const float e = __shfl_xor(d, 1);
        const float u = (n < 2) ? ((n == 0) ? (d - e) : (e - d)) : (d + e);
        const float v = __shfl_xor(u, 2);
        const float tr = (n < 2) ? u : v;
        const float ti = (n < 2) ? v : u;

        // null dots (select-free via A/B address swap; nr needs one sign)
        const float P = dot8(aA0, aA1, nwA0, nwA1);
        const float Q = dot8(aB0, aB1, nwB0, nwB1);
        const float nr = nsign * (P - Q);
        const float ni = dot8(aA0, aA1, nwB0, nwB1) + dot8(aB0, aB1, nwA0, nwA1);
        const float pw = (dot8(aA0, aA1, aA0, aA1) + dot8(aB0, aB1, aB0, aB1)) * 0.125f;

        // rotate buffers; issue load for frame t+3 (consumed 3 bodies later)
        aA0 = bA0; aA1 = bA1; aB0 = bB0; aB1 = bB1;
        bA0 = cA0; bA1 = cA1; bB0 = cB0; bB1 = cB1;
        if (t + 3 < te) {
            cA0 = *(const float4*)(xp + offA);
            cA1 = *(const float4*)(xp + offA + 4);
            cB0 = *(const float4*)(xp + offB);
            cB1 = *(const float4*)(xp + offB + 4);
        }
        xp += rowlen;

        if (t == 0) {  // exact asymmetric init from the reference
            phi_r = oma * tr * nr + ti * ni;
            phi_i = oma * ti * nr - tr * ni;
            psd   = oma * pw;
        } else {
            phi_r = a * phi_r + oma * (tr * nr + ti * ni);
            phi_i = a * phi_i + oma * (ti * nr - tr * ni);
            psd   = a * psd + oma * pw;
        }

        // f=256 on quad 0 of wave 0 (fh==1 blocks): weights from LDS, x direct
        float tr2 = 0.f, ti2 = 0.f;
        if (extra) {
            const float* xw = x + (size_t)(b * NT + t) * rowlen + 256 * NC;
            const float4 eA0 = *(const float4*)(xw + offA);
            const float4 eA1 = *(const float4*)(xw + offA + 4);
            const float4 eB0 = *(const float4*)(xw + offB);
            const float4 eB1 = *(const float4*)(xw + offB + 4);
            const float4 etw0 = *(const float4*)&s_w256[psel * 8];
            const float4 etw1 = *(const float4*)&s_w256[psel * 8 + 4];
            const float* nq = &s_w256[16 + n * 16];
            const float4 enA0 = *(const float4*)(nq + pA * 8);
            const float4 enA1 = *(const float4*)(nq + pA * 8 + 4);
            const float4 enB0 = *(const float4*)(nq + (1 - pA) * 8);
            const float4 enB1 = *(const float4*)(nq + (1 - pA) * 8 + 4);
            const float d2 = dot8(eA0, eA1, etw0, etw1);
            const float e2 = __shfl_xor(d2, 1);
            const float u2 = (n < 2) ? ((n == 0) ? (d2 - e2) : (e2 - d2)) : (d2 + e2);
            const float v2 = __shfl_xor(u2, 2);
            tr2 = (n < 2) ? u2 : v2;
            ti2 = (n < 2) ? v2 : u2;
            const float P2 = dot8(eA0, eA1, enA0, enA1);
            const float Q2 = dot8(eB0, eB1, enB0, enB1);
            const float nr2 = nsign * (P2 - Q2);
            const float ni2 = dot8(eA0, eA1, enB0, enB1) + dot8(eB0, eB1, enA0, enA1);
            const float pw2 = (dot8(eA0, eA1, eA0, eA1) + dot8(eB0, eB1, eB0, eB1)) * 0.125f;
            if (t == 0) {
                phi_r2 = oma * tr2 * nr2 + ti2 * ni2;
                phi_i2 = oma * ti2 * nr2 - tr2 * ni2;
                psd2   = oma * pw2;
            } else {
                phi_r2 = a * phi_r2 + oma * (tr2 * nr2 + ti2 * ni2);
                phi_i2 = a * phi_i2 + oma * (ti2 * nr2 - tr2 * ni2);
                psd2   = a * psd2 + oma * pw2;
            }
        }

        if (t >= t0) {
            const float phi = sqrtf(phi_r * phi_r + phi_i * phi_i);
            const float dcfv = fminf(fmaxf(phi / (psd + 1e-13f), 0.01f), 1.0f);
            const size_t bt = (size_t)(b * NT + t);
            out[(bt * NF + f) * NNUL + n] = dcfv;          // pre-ratio (final for t==0)
            if (n == 0) outT[(bt * 2 + 0) * NF + f] = tr;
            if (n == 1) outT[(bt * 2 + 1) * NF + f] = ti;
            if (extra) {
                const float phi2 = sqrtf(phi_r2 * phi_r2 + phi_i2 * phi_i2);
                const float dcf2v = fminf(fmaxf(phi2 / (psd2 + 1e-13f), 0.01f), 1.0f);
                out[(bt * NF + 256) * NNUL + n] = dcf2v;
                if (n == 0) outT[(bt * 2 + 0) * NF + 256] = tr2;
                if (n == 1) outT[(bt * 2 + 1) * NF + 256] = ti2;
            }
            if (fh == 0 && t >= 1 && wid < 5) {   // f in [5,70) lives in waves 0..4 of fh0
                float v_phi = in_red ? phi : 0.f;
                float v_psd = (in_red && n == 0) ? psd : 0.f;
                #pragma unroll
                for (int off = 4; off < 64; off <<= 1) {
                    v_phi += __shfl_xor(v_phi, off);
                    v_psd += __shfl_xor(v_psd, off);
                }
                float* cell = ws + bt * 5;
                if (lane < 4) atomicAdd(cell + lane, v_phi);
                if (lane == 0) atomicAdd(cell + 4, v_psd);
            }
        }
    }
}

// Kernel 2: per (b,t) ratio = clip(sum phi / (sum psd + 1e-10)); dcf = sqrt(dcf_pre*ratio).
__global__ __launch_bounds__(256) void dcf_ratio_kernel(
    float* __restrict__ out, const float* __restrict__ ws)
{
    const int bt = blockIdx.x;
    if ((bt % NT) == 0) return;   // t==0: no ratio term
    __shared__ float s_ratio[4];
    if (threadIdx.x < 4) {
        const float pre = ws[bt * 5 + 4];
        const float aft = ws[bt * 5 + threadIdx.x];
        s_ratio[threadIdx.x] = fminf(fmaxf(aft / (pre + 1e-10f), 0.01f), 1.0f);
    }
    __syncthreads();
    const float r0 = s_ratio[0], r1 = s_ratio[1], r2 = s_ratio[2], r3 = s_ratio[3];
    float4* dcf = (float4*)(out + (size_t)bt * (NF * NNUL));
    for (int i = threadIdx.x; i < NF; i += 256) {
        float4 v = dcf[i];
        v.x = sqrtf(v.x * r0);
        v.y = sqrtf(v.y * r1);
        v.z = sqrtf(v.z * r2);
        v.w = sqrtf(v.w * r3);
        dcf[i] = v;
    }
}

extern "C" void kernel_launch(void* const* d_in, const int* in_sizes, int n_in,
                              void* d_out, int out_size, void* d_ws, size_t ws_size,
                              hipStream_t stream) {
    const float* x       = (const float*)d_in[0];
    const int*   beam_id = (const int*)d_in[1];
    const float* targ_w  = (const float*)d_in[2];
    const float* null_w  = (const float*)d_in[3];
    float* out           = (float*)d_out;
    float* ws            = (float*)d_ws;

    hipMemsetAsync(ws, 0, (size_t)NB * NT * 5 * sizeof(float), stream);
    dcf_ema_kernel<<<dim3(NB * N_CHUNK * 2), dim3(512), 0, stream>>>(
        x, beam_id, targ_w, null_w, out, ws);
    dcf_ratio_kernel<<<dim3(NB * NT), dim3(256), 0, stream>>>(out, ws);
}

// Round 10
// 141.997 us; speedup vs baseline: 1.1554x; 1.1554x over previous
//
#include <hip/hip_runtime.h>

#define NB 8      // NUM_BLOCK
#define NT 500    // NUM_FRAME
#define NF 257    // NUM_BIN
#define NC 8      // NUM_CH
#define NNUL 4    // NUM_NULL
#define LOWF 5
#define HIGHF 70
#define S_CHUNK 8
#define WARM 4
#define N_CHUNK 63   // ceil(NT / S_CHUNK)
#define AL 0.35f

__device__ __forceinline__ float dot8(const float4& a0, const float4& a1,
                                      const float4& b0, const float4& b1) {
    return a0.x*b0.x + a0.y*b0.y + a0.z*b0.z + a0.w*b0.w
         + a1.x*b1.x + a1.y*b1.y + a1.z*b1.z + a1.w*b1.w;
}

// Kernel 1: EMA over an 8-frame chunk (+4 warm-up; missing-history weight
// alpha^5 ~ 0.5% rel -> ~0.01 absolute on dcf, threshold 0.475).
// EXACT R8 body (57 us, 60 VGPR, depth-1 prefetch) — R9's unroll-3 rotation
// bloated VALU ~26% for zero busy-time gain; reverted.
// launch_bounds(512,2): VGPR cap 128 (gfx950 rule: cap ~= 256/w; w>=4 caps
// <=64 and spills this body). Grid: (fh, b, chunk) = 1008 blocks x 512 thr.
__global__ __launch_bounds__(512, 2) void dcf_ema_kernel(
    const float* __restrict__ x,           // (NB,NT,2,NF,NC) fp32
    const int* __restrict__ beam_id,       // (NB,)
    const float* __restrict__ targ_w,      // (8,2,NF,NC) fp32
    const float* __restrict__ null_w,      // (8,NNUL,2,NF,NC) fp32
    float* __restrict__ out,               // fp32: dcf (NB,NT,NF,NNUL) then targ (NB,NT,2,NF)
    float* __restrict__ ws)                // (NB*NT,5): phi_sum[n], psd_sum — pre-zeroed
{
    const int tid = threadIdx.x;
    const int bid = blockIdx.x;
    const int fh = bid & 1;                // 0 -> f in [0,128), 1 -> [128,257)
    const int b  = (bid >> 1) & 7;
    const int k  = bid >> 4;
    const int t0 = k * S_CHUNK;
    const int te = min(NT, t0 + S_CHUNK);
    int ts = t0 - WARM; if (ts < 0) ts = 0;

    const int f = fh * 128 + (tid >> 2);   // 0..255
    const int n = tid & 3;
    const int wid = tid >> 6;
    const int lane = tid & 63;
    const bool extra = (fh == 1) && (tid < 4);   // quad 0 of wave 0 -> f=256

    __shared__ float s_w256[16 + 4 * 16];  // f=256 weights: twr,twi then per-n nwr,nwi

    const int beam = beam_id[b];
    const int pA = n & 1;                  // lane's "A" part: 0=real(even n), 1=imag(odd n)
    const int offA = pA * (NF * NC);
    const int offB = (1 - pA) * (NF * NC);
    const int psel = (n == 1 || n == 2) ? 1 : 0;   // targ part for this lane's partial
    const float nsign = pA ? -1.f : 1.f;

    // weights in registers: 6 float4 per thread
    float4 tw0, tw1, nwA0, nwA1, nwB0, nwB1;
    {
        const float* tp = targ_w + ((size_t)(beam * 2 + psel) * NF + f) * NC;
        tw0 = *(const float4*)(tp);  tw1 = *(const float4*)(tp + 4);
        const float* qp = null_w + ((size_t)((beam * NNUL + n) * 2) * NF + f) * NC;
        nwA0 = *(const float4*)(qp + offA);  nwA1 = *(const float4*)(qp + offA + 4);
        nwB0 = *(const float4*)(qp + offB);  nwB1 = *(const float4*)(qp + offB + 4);
    }
    if (tid < 16) {
        int p = tid >> 3, c = tid & 7;
        s_w256[tid] = targ_w[((size_t)(beam * 2 + p) * NF + 256) * NC + c];
    } else if (tid < 80) {
        int i = tid - 16;
        int nn = i >> 4, p = (i >> 3) & 1, c = i & 7;
        s_w256[tid] = null_w[((size_t)((beam * NNUL + nn) * 2 + p) * NF + 256) * NC + c];
    }
    __syncthreads();   // only block-wide barrier

    float phi_r = 0.f, phi_i = 0.f, psd = 0.f;
    float phi_r2 = 0.f, phi_i2 = 0.f, psd2 = 0.f;
    const float a = AL, oma = 1.0f - AL;
    const size_t rowlen = 2 * NF * NC;     // 4112 floats per (b,t)
    const bool in_red = (f >= LOWF) && (f < HIGHF);   // only in fh==0 waves 0..4

    // one-frame-ahead register prefetch (A = lane's parity part, B = other)
    const float* xrow = x + (size_t)(b * NT + ts) * rowlen + f * NC;
    float4 pA0 = *(const float4*)(xrow + offA);
    float4 pA1 = *(const float4*)(xrow + offA + 4);
    float4 pB0 = *(const float4*)(xrow + offB);
    float4 pB1 = *(const float4*)(xrow + offB + 4);

    float* outT = out + (size_t)NB * NT * NF * NNUL;

    for (int t = ts; t < te; ++t) {
        const float4 A0 = pA0, A1 = pA1, B0 = pB0, B1 = pB1;
        if (t + 1 < te) {
            const float* xr2 = x + (size_t)(b * NT + t + 1) * rowlen + f * NC;
            pA0 = *(const float4*)(xr2 + offA);
            pA1 = *(const float4*)(xr2 + offA + 4);
            pB0 = *(const float4*)(xr2 + offB);
            pB1 = *(const float4*)(xr2 + offB + 4);
        }

        // targ dots via quad butterfly: lane n's partial d covers
        // n0: xr.twr  n1: xi.twi  n2: xr.twi  n3: xi.twr
        const float d = dot8(A0, A1, tw0, tw1);
        const float e = __shfl_xor(d, 1);
        const float u = (n < 2) ? ((n == 0) ? (d - e) : (e - d)) : (d + e);
        const float v = __shfl_xor(u, 2);
        const float tr = (n < 2) ? u : v;
        const float ti = (n < 2) ? v : u;

        // null dots (select-free via A/B address swap; nr needs one sign)
        const float P = dot8(A0, A1, nwA0, nwA1);
        const float Q = dot8(B0, B1, nwB0, nwB1);
        const float nr = nsign * (P - Q);
        const float ni = dot8(A0, A1, nwB0, nwB1) + dot8(B0, B1, nwA0, nwA1);
        const float pw = (dot8(A0, A1, A0, A1) + dot8(B0, B1, B0, B1)) * 0.125f;

        if (t == 0) {  // exact asymmetric init from the reference
            phi_r = oma * tr * nr + ti * ni;
            phi_i = oma * ti * nr - tr * ni;
            psd   = oma * pw;
        } else {
            phi_r = a * phi_r + oma * (tr * nr + ti * ni);
            phi_i = a * phi_i + oma * (ti * nr - tr * ni);
            psd   = a * psd + oma * pw;
        }

        // f=256 on quad 0 of wave 0 (fh==1 blocks): weights from LDS, x direct
        float tr2 = 0.f, ti2 = 0.f;
        if (extra) {
            const float* xw = x + (size_t)(b * NT + t) * rowlen + 256 * NC;
            const float4 eA0 = *(const float4*)(xw + offA);
            const float4 eA1 = *(const float4*)(xw + offA + 4);
            const float4 eB0 = *(const float4*)(xw + offB);
            const float4 eB1 = *(const float4*)(xw + offB + 4);
            const float4 etw0 = *(const float4*)&s_w256[psel * 8];
            const float4 etw1 = *(const float4*)&s_w256[psel * 8 + 4];
            const float* nq = &s_w256[16 + n * 16];
            const float4 enA0 = *(const float4*)(nq + pA * 8);
            const float4 enA1 = *(const float4*)(nq + pA * 8 + 4);
            const float4 enB0 = *(const float4*)(nq + (1 - pA) * 8);
            const float4 enB1 = *(const float4*)(nq + (1 - pA) * 8 + 4);
            const float d2 = dot8(eA0, eA1, etw0, etw1);
            const float e2 = __shfl_xor(d2, 1);
            const float u2 = (n < 2) ? ((n == 0) ? (d2 - e2) : (e2 - d2)) : (d2 + e2);
            const float v2 = __shfl_xor(u2, 2);
            tr2 = (n < 2) ? u2 : v2;
            ti2 = (n < 2) ? v2 : u2;
            const float P2 = dot8(eA0, eA1, enA0, enA1);
            const float Q2 = dot8(eB0, eB1, enB0, enB1);
            const float nr2 = nsign * (P2 - Q2);
            const float ni2 = dot8(eA0, eA1, enB0, enB1) + dot8(eB0, eB1, enA0, enA1);
            const float pw2 = (dot8(eA0, eA1, eA0, eA1) + dot8(eB0, eB1, eB0, eB1)) * 0.125f;
            if (t == 0) {
                phi_r2 = oma * tr2 * nr2 + ti2 * ni2;
                phi_i2 = oma * ti2 * nr2 - tr2 * ni2;
                psd2   = oma * pw2;
            } else {
                phi_r2 = a * phi_r2 + oma * (tr2 * nr2 + ti2 * ni2);
                phi_i2 = a * phi_i2 + oma * (ti2 * nr2 - tr2 * ni2);
                psd2   = a * psd2 + oma * pw2;
            }
        }

        if (t >= t0) {
            const float phi = sqrtf(phi_r * phi_r + phi_i * phi_i);
            const float dcfv = fminf(fmaxf(phi / (psd + 1e-13f), 0.01f), 1.0f);
            const size_t bt = (size_t)(b * NT + t);
            out[(bt * NF + f) * NNUL + n] = dcfv;          // pre-ratio (final for t==0)
            if (n == 0) outT[(bt * 2 + 0) * NF + f] = tr;
            if (n == 1) outT[(bt * 2 + 1) * NF + f] = ti;
            if (extra) {
                const float phi2 = sqrtf(phi_r2 * phi_r2 + phi_i2 * phi_i2);
                const float dcf2v = fminf(fmaxf(phi2 / (psd2 + 1e-13f), 0.01f), 1.0f);
                out[(bt * NF + 256) * NNUL + n] = dcf2v;
                if (n == 0) outT[(bt * 2 + 0) * NF + 256] = tr2;
                if (n == 1) outT[(bt * 2 + 1) * NF + 256] = ti2;
            }
            if (fh == 0 && t >= 1 && wid < 5) {   // f in [5,70) lives in waves 0..4 of fh0
                float v_phi = in_red ? phi : 0.f;
                float v_psd = (in_red && n == 0) ? psd : 0.f;
                #pragma unroll
                for (int off = 4; off < 64; off <<= 1) {
                    v_phi += __shfl_xor(v_phi, off);
                    v_psd += __shfl_xor(v_psd, off);
                }
                float* cell = ws + bt * 5;
                if (lane < 4) atomicAdd(cell + lane, v_phi);
                if (lane == 0) atomicAdd(cell + 4, v_psd);
            }
        }
    }
}

// Kernel 2: per (b,t) ratio = clip(sum phi / (sum psd + 1e-10)); dcf = sqrt(dcf_pre*ratio).
__global__ __launch_bounds__(256) void dcf_ratio_kernel(
    float* __restrict__ out, const float* __restrict__ ws)
{
    const int bt = blockIdx.x;
    if ((bt % NT) == 0) return;   // t==0: no ratio term
    __shared__ float s_ratio[4];
    if (threadIdx.x < 4) {
        const float pre = ws[bt * 5 + 4];
        const float aft = ws[bt * 5 + threadIdx.x];
        s_ratio[threadIdx.x] = fminf(fmaxf(aft / (pre + 1e-10f), 0.01f), 1.0f);
    }
    __syncthreads();
    const float r0 = s_ratio[0], r1 = s_ratio[1], r2 = s_ratio[2], r3 = s_ratio[3];
    float4* dcf = (float4*)(out + (size_t)bt * (NF * NNUL));
    for (int i = threadIdx.x; i < NF; i += 256) {
        float4 v = dcf[i];
        v.x = sqrtf(v.x * r0);
        v.y = sqrtf(v.y * r1);
        v.z = sqrtf(v.z * r2);
        v.w = sqrtf(v.w * r3);
        dcf[i] = v;
    }
}

extern "C" void kernel_launch(void* const* d_in, const int* in_sizes, int n_in,
                              void* d_out, int out_size, void* d_ws, size_t ws_size,
                              hipStream_t stream) {
    const float* x       = (const float*)d_in[0];
    const int*   beam_id = (const int*)d_in[1];
    const float* targ_w  = (const float*)d_in[2];
    const float* null_w  = (const float*)d_in[3];
    float* out           = (float*)d_out;
    float* ws            = (float*)d_ws;

    hipMemsetAsync(ws, 0, (size_t)NB * NT * 5 * sizeof(float), stream);
    dcf_ema_kernel<<<dim3(NB * N_CHUNK * 2), dim3(512), 0, stream>>>(
        x, beam_id, targ_w, null_w, out, ws);
    dcf_ratio_kernel<<<dim3(NB * NT), dim3(256), 0, stream>>>(out, ws);
}